// Round 1
// 279.724 us; speedup vs baseline: 1.9178x; 1.9178x over previous
//
#include <hip/hip_runtime.h>

// Problem: VOCAB=10000, EMB=100, T=80, UNITS=256, BATCH=4096 — ALL FP32 I/O.
// out = sigmoid(h2_T);  h_l,t = tanh(x_l,t @ Wl + h_l,t-1 @ Ul + bl)
//
// v8 theory (from v7 counters): VGPR_Count=64 + WRITE_SIZE=48MB proved the
// "register-resident" B-frags actually spilled to scratch and were re-read
// every t-step (~400 KB/CU/step => ~6-7K cy of the 12.2K cy/step). Fix:
//  - 8 waves x 512 thr, waves_per_eu(2,2) => 256-VGPR budget, 1 block/CU.
//  - each wave owns TWO n-tiles (32 cols): W1/U1/W2 frags = 160 VGPR, fits.
//    A-frags shared across the 2 tiles => per-CU LDS state reads halve.
//  - U2 (128 KB) lives in dynamic LDS (staged once/block). Total LDS =
//    32 KB state + 128 KB U2 = 160 KB (gfx950 max/workgroup; opt-in attr).
// In-loop global traffic: 4-frag emb gather only.
#define BATCH 4096
#define TLEN  80
#define EMBD  100
#define UNITS 256
#define EMB_PAD 128            // emb K padded to 4 k-tiles of 32

typedef _Float16 f16;
typedef __attribute__((ext_vector_type(8))) _Float16 h8;   // 8 f16 = 4 VGPR MFMA A/B frag
typedef __attribute__((ext_vector_type(4))) float f32x4;   // MFMA C/D frag

__device__ __forceinline__ float fast_tanh(float x) {
  x = fminf(fmaxf(x, -15.f), 15.f);
  float e = __expf(-2.f * x);
  return (1.f - e) / (1.f + e);
}
__device__ __forceinline__ float fast_sigmoid(float x) {
  x = fminf(fmaxf(x, -30.f), 30.f);
  return 1.f / (1.f + __expf(-x));
}

// ---------------- workspace layout (3.02 MB; < 4 MB per-XCD L2) ------------
// B-frag layout (16x16x32, r7-verified, dtype-independent): lane holds
// B[k=quad*8+j][n=lane&15]; 8 contiguous f16 per (ktg,nt,lane) -> one dwordx4.
// ktg slots: W1 (K pad 128) = 0..3, U1 = 4..11, W2 = 12..19, U2 = 20..27.
#define KT_ALL 28
#define OFF_EHF ((size_t)0)
#define EHF_BYTES ((size_t)10000 * EMB_PAD * 2)             // 2,560,000
#define OFF_WF  EHF_BYTES
#define WF_BYTES ((size_t)KT_ALL * 16 * 64 * 8 * 2)         //   458,752
#define WS_NEED (OFF_WF + WF_BYTES)                          // 3,018,752 B

__device__ __forceinline__ size_t fidx(int ktg, int nt, int lane) {
  return (((size_t)ktg * 16 + nt) * 64 + lane) * 8;
}

// ---------------- precompute: weights -> swizzled fp16 B-frags (r10-verified)
__global__ __launch_bounds__(256) void k_split_w16(
    const float* __restrict__ W1, const float* __restrict__ U1,
    const float* __restrict__ W2, const float* __restrict__ U2,
    f16* __restrict__ wf)
{
  int gid = blockIdx.x * 256 + threadIdx.x;           // one per (ktg,nt,lane)
  if (gid >= KT_ALL * 16 * 64) return;
  int lane = gid & 63, nt = (gid >> 6) & 15, ktg = gid >> 10;
  const float* M; int Kact, ktl;
  if (ktg < 4)       { M = W1; Kact = EMBD;  ktl = ktg;      }
  else if (ktg < 12) { M = U1; Kact = UNITS; ktl = ktg - 4;  }
  else if (ktg < 20) { M = W2; Kact = UNITS; ktl = ktg - 12; }
  else               { M = U2; Kact = UNITS; ktl = ktg - 20; }
  int n = nt * 16 + (lane & 15);
  int kb = ktl * 32 + (lane >> 4) * 8;
  size_t base = fidx(ktg, nt, lane);
#pragma unroll
  for (int j = 0; j < 8; ++j) {
    int k = kb + j;
    wf[base + j] = (f16)((k < Kact) ? M[(size_t)k * UNITS + n] : 0.f);  // RNE
  }
}

// ---------------- precompute: emb -> padded fp16 (r10-verified) -------------
__global__ __launch_bounds__(256) void k_split_emb16(
    const float* __restrict__ emb, f16* __restrict__ ehf)
{
  int gid = blockIdx.x * 256 + threadIdx.x;
  if (gid >= 10000 * EMB_PAD) return;
  int row = gid >> 7, kk = gid & (EMB_PAD - 1);
  ehf[gid] = (f16)((kk < EMBD) ? emb[row * EMBD + kk] : 0.f);
}

#define MFMA16(A, B, C) __builtin_amdgcn_mfma_f32_16x16x32_f16(A, B, C, 0, 0, 0)

// store tanh result into next-step A-frag (single f16; layout r7-verified):
// elem (row=m, col=k): kt=col>>5, lane'=((col>>3)&3)*16+row, j'=col&7
__device__ __forceinline__ void store_frag1(f16* __restrict__ f, int col, int row, float v) {
  int a = (col >> 5) * 512 + (((col >> 3) & 3) * 16 + row) * 8 + (col & 7);
  f[a] = (f16)v;
}

// ---------------------------------------------------------------------------
// Main kernel v8: 512 threads = 8 waves, each wave owns n-tiles (2w, 2w+1).
// Register-resident weights (spill-free this time, verified by budget):
//   Bx0/Bx1 (W1, 8 frags=32 VGPR) + Bu1a/b (16=64) + Bw2a/b (16=64) = 160
//   + Ax(16) + accs(<=32) + temps  =>  ~220 of 256 budget.
// U2 in dynamic LDS (128 KB), layout [nt*8+kt][lane][8] so one base VGPR +
// imm offsets ((ntl*8+kt)*1024 <= 15360) covers all 16 reads/wave/step.
// ---------------------------------------------------------------------------
__global__ __launch_bounds__(512, 2)
__attribute__((amdgpu_waves_per_eu(2, 2)))
void rnn_ws4(
    const int* __restrict__ idx, const f16* __restrict__ ehf,
    const f16* __restrict__ wf,
    const float* __restrict__ b1, const float* __restrict__ b2,
    float* __restrict__ out)
{
  __shared__ __align__(16) f16 f1[2][4096];   // [buf][kt*512 + lane*8 + j]
  __shared__ __align__(16) f16 f2[2][4096];
  extern __shared__ f16 u2s[];                // 128 KB: [(nt*8+kt)*64+lane]*8

  const int tid  = threadIdx.x;
  const int lane = tid & 63;
  const int w    = tid >> 6;          // wave 0..7 -> n-tiles 2w, 2w+1
  const int m    = lane & 15;
  const int q    = lane >> 4;
  const int nt0  = 2 * w, nt1 = 2 * w + 1;
  const int c0   = nt0 * 16 + m;
  const int c1   = nt1 * 16 + m;
  const int b0   = blockIdx.x * 16;

  const float b1a = b1[c0], b1b = b1[c1];
  const float b2a = b2[c0], b2b = b2[c1];
  const int* tokp = idx + (size_t)(b0 + m) * TLEN;

  // -------- stage U2 into LDS once (128 KB / 512 thr = 16 h8 each) ---------
  for (int d = tid; d < 8192; d += 512) {             // d = (nt*8+kt)*64 + l
    int l = d & 63, g = d >> 6, nt = g >> 3, kt = g & 7;
    *(h8*)&u2s[(size_t)d * 8] = *(const h8*)(wf + fidx(20 + kt, nt, l));
  }

  // -------- persistent weight fragments: W1, U1, W2 (2 n-tiles each) -------
  h8 Bx0[4], Bx1[4], Bu1a[8], Bu1b[8], Bw2a[8], Bw2b[8];
#pragma unroll
  for (int kt = 0; kt < 4; ++kt) {
    Bx0[kt] = *(const h8*)(wf + fidx(kt, nt0, lane));
    Bx1[kt] = *(const h8*)(wf + fidx(kt, nt1, lane));
  }
#pragma unroll
  for (int kt = 0; kt < 8; ++kt) {
    Bu1a[kt] = *(const h8*)(wf + fidx(4 + kt, nt0, lane));
    Bu1b[kt] = *(const h8*)(wf + fidx(4 + kt, nt1, lane));
    Bw2a[kt] = *(const h8*)(wf + fidx(12 + kt, nt0, lane));
    Bw2b[kt] = *(const h8*)(wf + fidx(12 + kt, nt1, lane));
  }
  // pin: origin becomes the asm -> no remat; 160 VGPR fits the 256 budget
#pragma unroll
  for (int kt = 0; kt < 4; ++kt) {
    asm volatile("" : "+v"(Bx0[kt]));  asm volatile("" : "+v"(Bx1[kt]));
  }
#pragma unroll
  for (int kt = 0; kt < 8; ++kt) {
    asm volatile("" : "+v"(Bu1a[kt])); asm volatile("" : "+v"(Bu1b[kt]));
    asm volatile("" : "+v"(Bw2a[kt])); asm volatile("" : "+v"(Bw2b[kt]));
  }

  // t=0 embedding fragment (A rows = this lane's token row m; shared by tiles)
  h8 Ax[4];
  {
    const f16* eh = ehf + (size_t)tokp[0] * EMB_PAD + q * 8;
#pragma unroll
    for (int kt = 0; kt < 4; ++kt) Ax[kt] = *(const h8*)(eh + kt * 32);
  }

  for (int i = tid; i < 4096; i += 512) {
    f1[0][i] = (f16)0.f;
    f2[0][i] = (f16)0.f;
  }
  __syncthreads();                     // covers zero-init AND u2s staging

  for (int t = 0; t < TLEN; ++t) {
    const int p = t & 1, qb = p ^ 1;

    // ---- layer 1: a1 = b1 + x_t @ W1 + h1_old @ U1 (2 chains x 2 tiles) ---
    f32x4 xA0 = (f32x4){0.f, 0.f, 0.f, 0.f};
    f32x4 xB0 = (f32x4){0.f, 0.f, 0.f, 0.f};
    f32x4 xA1 = (f32x4){0.f, 0.f, 0.f, 0.f};
    f32x4 xB1 = (f32x4){0.f, 0.f, 0.f, 0.f};
#pragma unroll
    for (int kt = 0; kt < 4; ++kt) {
      xA0 = MFMA16(Ax[kt], Bx0[kt], xA0);
      xA1 = MFMA16(Ax[kt], Bx1[kt], xA1);
    }
#pragma unroll
    for (int kt = 0; kt < 8; ++kt) {
      h8 ah = *(const h8*)&f1[p][kt * 512 + lane * 8];
      if (kt & 1) { xA0 = MFMA16(ah, Bu1a[kt], xA0); xA1 = MFMA16(ah, Bu1b[kt], xA1); }
      else        { xB0 = MFMA16(ah, Bu1a[kt], xB0); xB1 = MFMA16(ah, Bu1b[kt], xB1); }
    }
#pragma unroll
    for (int r = 0; r < 4; ++r) {
      store_frag1(f1[qb], c0, q * 4 + r, fast_tanh(xA0[r] + xB0[r] + b1a));
      store_frag1(f1[qb], c1, q * 4 + r, fast_tanh(xA1[r] + xB1[r] + b1b));
    }

    // ---- layer 2 pre-barrier half: h2_old @ U2 (U2 frags from LDS) --------
    f32x4 yA0 = (f32x4){0.f, 0.f, 0.f, 0.f};
    f32x4 yB0 = (f32x4){0.f, 0.f, 0.f, 0.f};
    f32x4 yA1 = (f32x4){0.f, 0.f, 0.f, 0.f};
    f32x4 yB1 = (f32x4){0.f, 0.f, 0.f, 0.f};
#pragma unroll
    for (int kt = 0; kt < 8; ++kt) {
      h8 ah = *(const h8*)&f2[p][kt * 512 + lane * 8];
      h8 u0 = *(const h8*)&u2s[((nt0 * 8 + kt) * 64 + lane) * 8];
      h8 u1 = *(const h8*)&u2s[((nt1 * 8 + kt) * 64 + lane) * 8];
      if (kt & 1) { yA0 = MFMA16(ah, u0, yA0); yA1 = MFMA16(ah, u1, yA1); }
      else        { yB0 = MFMA16(ah, u0, yB0); yB1 = MFMA16(ah, u1, yB1); }
    }
    __syncthreads();                           // barrier 1: f1[qb] visible

    // ---- layer 2 post-barrier half: h1_new @ W2 ----
#pragma unroll
    for (int kt = 0; kt < 8; ++kt) {
      h8 ah = *(const h8*)&f1[qb][kt * 512 + lane * 8];
      if (kt & 1) { yA0 = MFMA16(ah, Bw2a[kt], yA0); yA1 = MFMA16(ah, Bw2b[kt], yA1); }
      else        { yB0 = MFMA16(ah, Bw2a[kt], yB0); yB1 = MFMA16(ah, Bw2b[kt], yB1); }
    }
    // prefetch next step's embedding fragment (hidden under epilogue+barrier)
    if (t + 1 < TLEN) {
      const f16* eh = ehf + (size_t)tokp[t + 1] * EMB_PAD + q * 8;
#pragma unroll
      for (int kt = 0; kt < 4; ++kt) Ax[kt] = *(const h8*)(eh + kt * 32);
    }
#pragma unroll
    for (int r = 0; r < 4; ++r) {
      int row = q * 4 + r;
      float t0 = fast_tanh(yA0[r] + yB0[r] + b2a);
      float t1 = fast_tanh(yA1[r] + yB1[r] + b2b);
      store_frag1(f2[qb], c0, row, t0);
      store_frag1(f2[qb], c1, row, t1);
      if (t == TLEN - 1) {
        out[(size_t)(b0 + row) * UNITS + c0] = fast_sigmoid(t0);
        out[(size_t)(b0 + row) * UNITS + c1] = fast_sigmoid(t1);
      }
    }
    __syncthreads();                           // barrier 2: f2[qb] visible
  }
}

// ---------------------------------------------------------------------------
extern "C" void kernel_launch(void* const* d_in, const int* in_sizes, int n_in,
                              void* d_out, int out_size, void* d_ws, size_t ws_size,
                              hipStream_t stream)
{
  const int*   idx = (const int*)d_in[0];
  const float* emb = (const float*)d_in[1];
  const float* W1  = (const float*)d_in[2];
  const float* U1  = (const float*)d_in[3];
  const float* b1  = (const float*)d_in[4];
  const float* W2  = (const float*)d_in[5];
  const float* U2  = (const float*)d_in[6];
  const float* b2  = (const float*)d_in[7];
  // d_in[8] (Wd), d_in[9] (bd) dead in the reference output.
  float* out = (float*)d_out;

  // 128 KB dynamic + 32 KB static = 160 KB LDS/workgroup (gfx950 max; AITER
  // fmha ships 160KB-LDS workgroups). Opt-in once via func attribute.
  static bool attr_done = false;
  if (!attr_done) {
    (void)hipFuncSetAttribute((const void*)rnn_ws4,
                              hipFuncAttributeMaxDynamicSharedMemorySize,
                              131072);
    attr_done = true;
  }

  f16* ehf = (f16*)((char*)d_ws + OFF_EHF);
  f16* wf  = (f16*)((char*)d_ws + OFF_WF);
  k_split_emb16<<<(10000 * EMB_PAD + 255) / 256, 256, 0, stream>>>(emb, ehf);
  k_split_w16<<<(KT_ALL * 16 * 64 + 255) / 256, 256, 0, stream>>>(W1, U1, W2, U2, wf);
  rnn_ws4<<<BATCH / 16, 512, 131072, stream>>>(idx, ehf, wf, b1, b2, out);
}